// Round 4
// baseline (248.627 us; speedup 1.0000x reference)
//
#include <hip/hip_runtime.h>

// EquivariantLinear: out[pos, c, m] = pw * sum_k x[pos, k, m] * W_{l(m)}[k, c]
// pos = 32768, C_IN = C_OUT = 256, FEAT = 9 (irreps 1,3,5), pw = 1/16.
// R6: m-split + c-split residency fix. Each block = 16 pos x 128 ch x one
// m-half (m0-3 or m4-8). Grid 8192 = 2048 tiles x 2 mhalf x 2 chalf; siblings
// are 8/16/24 apart in blockIdx -> same XCD -> x re-reads are L2 hits.
// Total MFMA / convert / ds_write work across siblings == R2 exactly; only
// global-load issues replicate (L2-served). Per block: LDS 42.2 KB (3 blk/CU),
// acc 16-20 regs, unified ~70 -> launch_bounds(512,6) gives 24 waves/CU in 3
// independent phase-chains (vs R2's ~12 waves in 1.5 chains).
// Converts use v_cvt_pk_bf16_f32 (RNE, 2-in-1) instead of 4-op bitwise.

typedef float f32x4 __attribute__((ext_vector_type(4)));
typedef float f32x4u __attribute__((ext_vector_type(4), aligned(4)));
typedef short s16x8 __attribute__((ext_vector_type(8)));

#define POSB 16                       // positions per tile
#define XS_KS 264                     // padded k-stride (elems)
#define XS_MS (POSB * XS_KS)          // 4224 elems per m-plane
#define PLANES_MAX 5
#define SMEM_BYTES (PLANES_MAX * XS_MS * 2)  // 42240 B -> 3 blocks/CU

__device__ __forceinline__ unsigned short f2bf(float f) {
  unsigned u = __float_as_uint(f);
  return (unsigned short)((u + 0x7FFFu + ((u >> 16) & 1u)) >> 16);
}

__device__ __forceinline__ unsigned cvt_pk_bf16(float lo, float hi) {
  unsigned r;
  asm("v_cvt_pk_bf16_f32 %0, %1, %2" : "=v"(r) : "v"(lo), "v"(hi));
  return r;
}

// ---- prep: W^T bf16 image in ws: wt[irr][c][k] = pw * w_irr[k][c] ----
__global__ void prep_w(const float* __restrict__ w0, const float* __restrict__ w1,
                       const float* __restrict__ w2, unsigned short* __restrict__ wt) {
  const int b = blockIdx.x;
  const int irr = b / 16;
  const int tile = b % 16;
  const int k0 = (tile >> 2) << 6;
  const int c0 = (tile & 3) << 6;
  const float* w = (irr == 0) ? w0 : ((irr == 1) ? w1 : w2);
  __shared__ float lt[64 * 65];
  const int t = threadIdx.x;
#pragma unroll
  for (int i = 0; i < 16; ++i) {
    int e = t + (i << 8);
    int kk = e >> 6, cc = e & 63;
    lt[cc * 65 + kk] = w[(k0 + kk) * 256 + (c0 + cc)];
  }
  __syncthreads();
#pragma unroll
  for (int i = 0; i < 16; ++i) {
    int e = t + (i << 8);
    int cc = e >> 6, kk = e & 63;
    wt[irr * 65536 + (c0 + cc) * 256 + (k0 + kk)] = f2bf(lt[cc * 65 + kk] * 0.0625f);
  }
}

// stage this block's m-planes [MBASE, MBASE+NP) into xs; loads of x vectors
// not overlapping the m-subset are DCE'd per template instantiation.
template <int MBASE, int NP>
__device__ __forceinline__ void stage_half(const float* __restrict__ xb,
                                           unsigned short* __restrict__ xs, int t) {
#pragma unroll
  for (int i = 0; i < 2; ++i) {
    const int p = t + (i << 9);        // 0..1023 = pos(4b) x kquad(6b)
    const int pos = p >> 6;
    const int kq = (p & 63) << 2;      // k base, multiple of 4
    const float* src = xb + p * 36;    // 144-B chunk: (k_local*9 + m)
    float f[36];
#pragma unroll
    for (int j = 0; j < 9; ++j) {
      f32x4 v = *reinterpret_cast<const f32x4*>(src + j * 4);
      f[j * 4 + 0] = v[0]; f[j * 4 + 1] = v[1];
      f[j * 4 + 2] = v[2]; f[j * 4 + 3] = v[3];
    }
#pragma unroll
    for (int mm = 0; mm < NP; ++mm) {
      const int m = MBASE + mm;
      unsigned lo = cvt_pk_bf16(f[m], f[9 + m]);        // k_local 0,1
      unsigned hi = cvt_pk_bf16(f[18 + m], f[27 + m]);  // k_local 2,3
      unsigned long long pk =
          (unsigned long long)lo | ((unsigned long long)hi << 32);
      *reinterpret_cast<unsigned long long*>(xs + mm * XS_MS + pos * XS_KS + kq) = pk;
    }
  }
}

// ---- main: 8192 blocks x 512 threads (8 waves), 3 blocks/CU ----
__global__ __launch_bounds__(512, 6) void eqlin_main(
    const float* __restrict__ x, const unsigned short* __restrict__ wt,
    float* __restrict__ out) {
  extern __shared__ char smem[];
  unsigned short* xs = reinterpret_cast<unsigned short*>(smem);  // [NP][16][264]

  const int t = threadIdx.x;
  const int b = blockIdx.x;
  // siblings (same tile; other mhalf/chalf) are 8/16/24 apart -> same XCD
  const int grp = b >> 5;
  const int sub = b & 31;
  const long long tile = (long long)grp * 8 + (sub & 7);  // 0..2047
  const int mhalf = (sub >> 3) & 1;
  const int chalf = sub >> 4;

  const float* xb = x + tile * (POSB * 2304);

  if (mhalf == 0) stage_half<0, 4>(xb, xs, t);
  else            stage_half<4, 5>(xb, xs, t);
  __syncthreads();

  const int w = t >> 6;
  const int l = t & 63;
  const int cr = l & 15;          // A row (=pos) / B col (=c in tile)
  const int kg = (l >> 4) << 3;   // k-chunk base 0/8/16/24
  const int c = chalf * 128 + (w << 4) + cr;   // 16 channels per wave
  const int g = l >> 4;           // pos quad

  const unsigned short* xsA = xs + cr * XS_KS + kg;
  const unsigned short* wtB = wt + c * 256 + kg;

  if (mhalf == 0) {
    f32x4 acc[4];
#pragma unroll
    for (int m = 0; m < 4; ++m) acc[m] = (f32x4){0.f, 0.f, 0.f, 0.f};
#pragma unroll 2
    for (int ks = 0; ks < 8; ++ks) {
      const int kk = ks << 5;
      s16x8 b0 = *reinterpret_cast<const s16x8*>(wtB + kk);           // irr0
      s16x8 b1 = *reinterpret_cast<const s16x8*>(wtB + 65536 + kk);   // irr1
      {
        s16x8 a = *reinterpret_cast<const s16x8*>(xsA + kk);
        acc[0] = __builtin_amdgcn_mfma_f32_16x16x32_bf16(a, b0, acc[0], 0, 0, 0);
      }
#pragma unroll
      for (int m = 1; m < 4; ++m) {
        s16x8 a = *reinterpret_cast<const s16x8*>(xsA + m * XS_MS + kk);
        acc[m] = __builtin_amdgcn_mfma_f32_16x16x32_bf16(a, b1, acc[m], 0, 0, 0);
      }
    }
    // store m0..3: one 16-B chunk per (pos, c)
#pragma unroll
    for (int j = 0; j < 4; ++j) {
      float* o = out + ((tile * POSB + (g << 2) + j) * 256 + c) * 9;
      f32x4u v0 = {acc[0][j], acc[1][j], acc[2][j], acc[3][j]};
      *reinterpret_cast<f32x4u*>(o) = v0;
    }
  } else {
    f32x4 acc[5];
#pragma unroll
    for (int m = 0; m < 5; ++m) acc[m] = (f32x4){0.f, 0.f, 0.f, 0.f};
#pragma unroll 2
    for (int ks = 0; ks < 8; ++ks) {
      const int kk = ks << 5;
      s16x8 b2 = *reinterpret_cast<const s16x8*>(wtB + 131072 + kk);  // irr2
#pragma unroll
      for (int m = 0; m < 5; ++m) {
        s16x8 a = *reinterpret_cast<const s16x8*>(xsA + m * XS_MS + kk);
        acc[m] = __builtin_amdgcn_mfma_f32_16x16x32_bf16(a, b2, acc[m], 0, 0, 0);
      }
    }
    // store m4..8: 16 B + 4 B per (pos, c)
#pragma unroll
    for (int j = 0; j < 4; ++j) {
      float* o = out + ((tile * POSB + (g << 2) + j) * 256 + c) * 9 + 4;
      f32x4u v1 = {acc[0][j], acc[1][j], acc[2][j], acc[3][j]};
      *reinterpret_cast<f32x4u*>(o) = v1;
      o[4] = acc[4][j];
    }
  }
}

extern "C" void kernel_launch(void* const* d_in, const int* in_sizes, int n_in,
                              void* d_out, int out_size, void* d_ws, size_t ws_size,
                              hipStream_t stream) {
  const float* x = (const float*)d_in[0];
  const float* w0 = (const float*)d_in[1];
  const float* w1 = (const float*)d_in[2];
  const float* w2 = (const float*)d_in[3];
  unsigned short* wt = (unsigned short*)d_ws;  // 3*256*256 bf16 = 384 KB
  float* out = (float*)d_out;

  prep_w<<<48, 256, 0, stream>>>(w0, w1, w2, wt);

  (void)hipFuncSetAttribute(reinterpret_cast<const void*>(eqlin_main),
                            hipFuncAttributeMaxDynamicSharedMemorySize, SMEM_BYTES);
  eqlin_main<<<8192, 512, SMEM_BYTES, stream>>>(x, wt, out);
}

// Round 5
// 180.167 us; speedup vs baseline: 1.3800x; 1.3800x over previous
//
#include <hip/hip_runtime.h>

// EquivariantLinear: out[pos, c, m] = pw * sum_k x[pos, k, m] * W_{l(m)}[k, c]
// pos = 32768, C_IN = C_OUT = 256, FEAT = 9 (irreps 1,3,5), pw = 1/16.
// R7 = R2 skeleton (2048 blocks x 512 thr, POSB=16, 76KB LDS, LDS-staged
// coalesced output) with a re-coalesced stage phase:
//  - thread unit = 36-B m-row (9 floats of one (pos,k)), 8 units/thread,
//    lane stride 36 B -> ~18 cache lines per load instr (vs ~72 for the old
//    144-B units). All 24 load instrs issued before any convert (MLP 24).
//  - converts via v_cvt_pk_bf16_f32 (1 op / 2 values).
//  - LDS writes: 9x ds_write_b16 per unit, consecutive lanes = consecutive k
//    -> 2-B stride, 2 lanes/bank = conflict-free.
// Compute + out-stage phases identical to R2 (best measured).

typedef float f32x4 __attribute__((ext_vector_type(4)));
typedef float f32x4u __attribute__((ext_vector_type(4), aligned(4)));
typedef short s16x8 __attribute__((ext_vector_type(8)));

#define POSB 16                      // positions per block
#define XS_KS 264                    // padded k-stride (elems)
#define XS_MS (POSB * XS_KS)         // 4224 elems per m-plane
#define SMEM_BYTES (9 * XS_MS * 2)   // 76032 B
#define STG_ROW 148                  // out-stage row stride (floats); row=144 used
// per-wave out-stage: 16*148*4 = 9472 B; 8 waves = 75776 <= 76032 (aliases xs)

__device__ __forceinline__ unsigned short f2bf(float f) {
  unsigned u = __float_as_uint(f);
  return (unsigned short)((u + 0x7FFFu + ((u >> 16) & 1u)) >> 16);
}

__device__ __forceinline__ unsigned cvt_pk_bf16(float lo, float hi) {
  unsigned r;
  asm("v_cvt_pk_bf16_f32 %0, %1, %2" : "=v"(r) : "v"(lo), "v"(hi));
  return r;
}

// ---- prep: W^T bf16 image in ws: wt[irr][c][k] = pw * w_irr[k][c] ----
__global__ void prep_w(const float* __restrict__ w0, const float* __restrict__ w1,
                       const float* __restrict__ w2, unsigned short* __restrict__ wt) {
  const int b = blockIdx.x;
  const int irr = b / 16;
  const int tile = b % 16;
  const int k0 = (tile >> 2) << 6;
  const int c0 = (tile & 3) << 6;
  const float* w = (irr == 0) ? w0 : ((irr == 1) ? w1 : w2);
  __shared__ float lt[64 * 65];
  const int t = threadIdx.x;
#pragma unroll
  for (int i = 0; i < 16; ++i) {
    int e = t + (i << 8);
    int kk = e >> 6, cc = e & 63;
    lt[cc * 65 + kk] = w[(k0 + kk) * 256 + (c0 + cc)];
  }
  __syncthreads();
#pragma unroll
  for (int i = 0; i < 16; ++i) {
    int e = t + (i << 8);
    int cc = e >> 6, kk = e & 63;
    wt[irr * 65536 + (c0 + cc) * 256 + (k0 + kk)] = f2bf(lt[cc * 65 + kk] * 0.0625f);
  }
}

// ---- main: 2048 blocks x 512 threads (8 waves), 2 blocks/CU ----
__global__ __launch_bounds__(512, 4) void eqlin_main(
    const float* __restrict__ x, const unsigned short* __restrict__ wt,
    float* __restrict__ out) {
  extern __shared__ char smem[];
  unsigned short* xs = reinterpret_cast<unsigned short*>(smem);  // [9][16][264] bf16

  const int t = threadIdx.x;
  const long long blk = blockIdx.x;
  const float* xb = x + blk * (POSB * 2304);

  // ---- stage x -> LDS bf16 [m][pos][k]: 4096 36-B units, 8 per thread ----
  {
    f32x4u va[8], vb[8];
    float vc[8];
#pragma unroll
    for (int i = 0; i < 8; ++i) {
      const float* s = xb + (t + (i << 9)) * 9;
      va[i] = *reinterpret_cast<const f32x4u*>(s);
      vb[i] = *reinterpret_cast<const f32x4u*>(s + 4);
      vc[i] = s[8];
    }
#pragma unroll
    for (int i = 0; i < 8; ++i) {
      const int u = t + (i << 9);
      const int pos = u >> 8;        // 0..15
      const int k = u & 255;
      unsigned short* base = xs + pos * XS_KS + k;
      unsigned p01 = cvt_pk_bf16(va[i][0], va[i][1]);
      unsigned p23 = cvt_pk_bf16(va[i][2], va[i][3]);
      unsigned p45 = cvt_pk_bf16(vb[i][0], vb[i][1]);
      unsigned p67 = cvt_pk_bf16(vb[i][2], vb[i][3]);
      base[0 * XS_MS] = (unsigned short)p01;
      base[1 * XS_MS] = (unsigned short)(p01 >> 16);
      base[2 * XS_MS] = (unsigned short)p23;
      base[3 * XS_MS] = (unsigned short)(p23 >> 16);
      base[4 * XS_MS] = (unsigned short)p45;
      base[5 * XS_MS] = (unsigned short)(p45 >> 16);
      base[6 * XS_MS] = (unsigned short)p67;
      base[7 * XS_MS] = (unsigned short)(p67 >> 16);
      base[8 * XS_MS] = f2bf(vc[i]);
    }
  }
  __syncthreads();

  const int w = t >> 6;
  const int l = t & 63;
  const int cr = l & 15;          // A row (=pos) / B col (=c in tile)
  const int kg = (l >> 4) << 3;   // k-chunk base 0/8/16/24
  const int c0 = w << 5;          // 32 channels per wave

  const unsigned short* xsA = xs + cr * XS_KS + kg;
  const unsigned short* wtB = wt + (c0 + cr) * 256 + kg;

  f32x4 accA[4][2];  // m = 0..3
#pragma unroll
  for (int m = 0; m < 4; ++m)
#pragma unroll
    for (int ct = 0; ct < 2; ++ct) accA[m][ct] = (f32x4){0.f, 0.f, 0.f, 0.f};

  // pass 1: m 0..3 (irr0 for m0, irr1 for m1..3)
#pragma unroll 2
  for (int ks = 0; ks < 8; ++ks) {
    const int kk = ks << 5;
    s16x8 b00 = *reinterpret_cast<const s16x8*>(wtB + kk);
    s16x8 b01 = *reinterpret_cast<const s16x8*>(wtB + 4096 + kk);
    s16x8 b10 = *reinterpret_cast<const s16x8*>(wtB + 65536 + kk);
    s16x8 b11 = *reinterpret_cast<const s16x8*>(wtB + 65536 + 4096 + kk);
    {
      s16x8 a = *reinterpret_cast<const s16x8*>(xsA + kk);
      accA[0][0] = __builtin_amdgcn_mfma_f32_16x16x32_bf16(a, b00, accA[0][0], 0, 0, 0);
      accA[0][1] = __builtin_amdgcn_mfma_f32_16x16x32_bf16(a, b01, accA[0][1], 0, 0, 0);
    }
#pragma unroll
    for (int m = 1; m < 4; ++m) {
      s16x8 a = *reinterpret_cast<const s16x8*>(xsA + m * XS_MS + kk);
      accA[m][0] = __builtin_amdgcn_mfma_f32_16x16x32_bf16(a, b10, accA[m][0], 0, 0, 0);
      accA[m][1] = __builtin_amdgcn_mfma_f32_16x16x32_bf16(a, b11, accA[m][1], 0, 0, 0);
    }
  }

  f32x4 accB[5][2];  // m = 4..8 (irr2)
#pragma unroll
  for (int m = 0; m < 5; ++m)
#pragma unroll
    for (int ct = 0; ct < 2; ++ct) accB[m][ct] = (f32x4){0.f, 0.f, 0.f, 0.f};

  // pass 2: m 4..8
#pragma unroll 2
  for (int ks = 0; ks < 8; ++ks) {
    const int kk = ks << 5;
    s16x8 b20 = *reinterpret_cast<const s16x8*>(wtB + 2 * 65536 + kk);
    s16x8 b21 = *reinterpret_cast<const s16x8*>(wtB + 2 * 65536 + 4096 + kk);
#pragma unroll
    for (int m = 0; m < 5; ++m) {
      s16x8 a = *reinterpret_cast<const s16x8*>(xsA + (m + 4) * XS_MS + kk);
      accB[m][0] = __builtin_amdgcn_mfma_f32_16x16x32_bf16(a, b20, accB[m][0], 0, 0, 0);
      accB[m][1] = __builtin_amdgcn_mfma_f32_16x16x32_bf16(a, b21, accB[m][1], 0, 0, 0);
    }
  }
  __syncthreads();  // xs fully consumed by ALL waves; stage may alias it

  // ---- per-wave out-stage (9472 B slice of smem), wave-internal sync only ----
  float* stgw = reinterpret_cast<float*>(smem) + w * (POSB * STG_ROW);
  const int posb = (l >> 4) << 2;
  f32x4* o4 = reinterpret_cast<f32x4*>(out) + blk * 9216 + w * 72;

#pragma unroll
  for (int ct = 0; ct < 2; ++ct) {
    // scatter acc -> stgw[pos][cr*9 + m]  (fp32, ~2-way banks: free)
#pragma unroll
    for (int m = 0; m < 9; ++m) {
#pragma unroll
      for (int j = 0; j < 4; ++j) {
        float v = (m < 4) ? accA[m][ct][j] : accB[m - 4][ct][j];
        stgw[(posb + j) * STG_ROW + cr * 9 + m] = v;
      }
    }
    asm volatile("s_waitcnt lgkmcnt(0)" ::: "memory");
    // coalesced float4 store of this wave's contiguous 16c x 9m slice
#pragma unroll
    for (int q = 0; q < 9; ++q) {
      const int e = l + (q << 6);                 // 0..575 float4s
      const int pos = (int)((unsigned)e / 36u);
      const int rem = e - pos * 36;
      f32x4 v = *reinterpret_cast<const f32x4*>(stgw + pos * STG_ROW + (rem << 2));
      o4[pos * 576 + ct * 36 + rem] = v;
    }
    asm volatile("s_waitcnt lgkmcnt(0)" ::: "memory");  // drain reads before next ct writes
  }
}

extern "C" void kernel_launch(void* const* d_in, const int* in_sizes, int n_in,
                              void* d_out, int out_size, void* d_ws, size_t ws_size,
                              hipStream_t stream) {
  const float* x = (const float*)d_in[0];
  const float* w0 = (const float*)d_in[1];
  const float* w1 = (const float*)d_in[2];
  const float* w2 = (const float*)d_in[3];
  unsigned short* wt = (unsigned short*)d_ws;  // 3*256*256 bf16 = 384 KB
  float* out = (float*)d_out;

  prep_w<<<48, 256, 0, stream>>>(w0, w1, w2, wt);

  (void)hipFuncSetAttribute(reinterpret_cast<const void*>(eqlin_main),
                            hipFuncAttributeMaxDynamicSharedMemorySize, SMEM_BYTES);
  eqlin_main<<<2048, 512, SMEM_BYTES, stream>>>(x, wt, out);
}

// Round 6
// 162.728 us; speedup vs baseline: 1.5279x; 1.1072x over previous
//
#include <hip/hip_runtime.h>

// EquivariantLinear: out[pos, c, m] = pw * sum_k x[pos, k, m] * W_{l(m)}[k, c]
// pos = 32768, C_IN = C_OUT = 256, FEAT = 9 (irreps 1,3,5), pw = 1/16.
// R8 = R7 + NON-TEMPORAL output stores. Output (297 MB/iter) is write-once,
// never re-read; by default it flows through L2/L3 and evicts x, capping x's
// cross-iteration L3 hit rate at ~47% (FETCH 155 MB vs 295 MB logical).
// nt stores keep out from polluting L3 -> x stays resident -> HBM read
// traffic drops. Stores are full-line (1 KB contiguous per wave instr) so
// streaming costs nothing in write-combining. Everything else == R7.

typedef float f32x4 __attribute__((ext_vector_type(4)));
typedef float f32x4u __attribute__((ext_vector_type(4), aligned(4)));
typedef short s16x8 __attribute__((ext_vector_type(8)));

#define POSB 16                      // positions per block
#define XS_KS 264                    // padded k-stride (elems)
#define XS_MS (POSB * XS_KS)         // 4224 elems per m-plane
#define SMEM_BYTES (9 * XS_MS * 2)   // 76032 B
#define STG_ROW 148                  // out-stage row stride (floats); row=144 used
// per-wave out-stage: 16*148*4 = 9472 B; 8 waves = 75776 <= 76032 (aliases xs)

__device__ __forceinline__ unsigned short f2bf(float f) {
  unsigned u = __float_as_uint(f);
  return (unsigned short)((u + 0x7FFFu + ((u >> 16) & 1u)) >> 16);
}

__device__ __forceinline__ unsigned cvt_pk_bf16(float lo, float hi) {
  unsigned r;
  asm("v_cvt_pk_bf16_f32 %0, %1, %2" : "=v"(r) : "v"(lo), "v"(hi));
  return r;
}

// ---- prep: W^T bf16 image in ws: wt[irr][c][k] = pw * w_irr[k][c] ----
__global__ void prep_w(const float* __restrict__ w0, const float* __restrict__ w1,
                       const float* __restrict__ w2, unsigned short* __restrict__ wt) {
  const int b = blockIdx.x;
  const int irr = b / 16;
  const int tile = b % 16;
  const int k0 = (tile >> 2) << 6;
  const int c0 = (tile & 3) << 6;
  const float* w = (irr == 0) ? w0 : ((irr == 1) ? w1 : w2);
  __shared__ float lt[64 * 65];
  const int t = threadIdx.x;
#pragma unroll
  for (int i = 0; i < 16; ++i) {
    int e = t + (i << 8);
    int kk = e >> 6, cc = e & 63;
    lt[cc * 65 + kk] = w[(k0 + kk) * 256 + (c0 + cc)];
  }
  __syncthreads();
#pragma unroll
  for (int i = 0; i < 16; ++i) {
    int e = t + (i << 8);
    int cc = e >> 6, kk = e & 63;
    wt[irr * 65536 + (c0 + cc) * 256 + (k0 + kk)] = f2bf(lt[cc * 65 + kk] * 0.0625f);
  }
}

// ---- main: 2048 blocks x 512 threads (8 waves), 2 blocks/CU ----
__global__ __launch_bounds__(512, 4) void eqlin_main(
    const float* __restrict__ x, const unsigned short* __restrict__ wt,
    float* __restrict__ out) {
  extern __shared__ char smem[];
  unsigned short* xs = reinterpret_cast<unsigned short*>(smem);  // [9][16][264] bf16

  const int t = threadIdx.x;
  const long long blk = blockIdx.x;
  const float* xb = x + blk * (POSB * 2304);

  // ---- stage x -> LDS bf16 [m][pos][k]: 4096 36-B units, 8 per thread ----
  {
    f32x4u va[8], vb[8];
    float vc[8];
#pragma unroll
    for (int i = 0; i < 8; ++i) {
      const float* s = xb + (t + (i << 9)) * 9;
      va[i] = *reinterpret_cast<const f32x4u*>(s);
      vb[i] = *reinterpret_cast<const f32x4u*>(s + 4);
      vc[i] = s[8];
    }
#pragma unroll
    for (int i = 0; i < 8; ++i) {
      const int u = t + (i << 9);
      const int pos = u >> 8;        // 0..15
      const int k = u & 255;
      unsigned short* base = xs + pos * XS_KS + k;
      unsigned p01 = cvt_pk_bf16(va[i][0], va[i][1]);
      unsigned p23 = cvt_pk_bf16(va[i][2], va[i][3]);
      unsigned p45 = cvt_pk_bf16(vb[i][0], vb[i][1]);
      unsigned p67 = cvt_pk_bf16(vb[i][2], vb[i][3]);
      base[0 * XS_MS] = (unsigned short)p01;
      base[1 * XS_MS] = (unsigned short)(p01 >> 16);
      base[2 * XS_MS] = (unsigned short)p23;
      base[3 * XS_MS] = (unsigned short)(p23 >> 16);
      base[4 * XS_MS] = (unsigned short)p45;
      base[5 * XS_MS] = (unsigned short)(p45 >> 16);
      base[6 * XS_MS] = (unsigned short)p67;
      base[7 * XS_MS] = (unsigned short)(p67 >> 16);
      base[8 * XS_MS] = f2bf(vc[i]);
    }
  }
  __syncthreads();

  const int w = t >> 6;
  const int l = t & 63;
  const int cr = l & 15;          // A row (=pos) / B col (=c in tile)
  const int kg = (l >> 4) << 3;   // k-chunk base 0/8/16/24
  const int c0 = w << 5;          // 32 channels per wave

  const unsigned short* xsA = xs + cr * XS_KS + kg;
  const unsigned short* wtB = wt + (c0 + cr) * 256 + kg;

  f32x4 accA[4][2];  // m = 0..3
#pragma unroll
  for (int m = 0; m < 4; ++m)
#pragma unroll
    for (int ct = 0; ct < 2; ++ct) accA[m][ct] = (f32x4){0.f, 0.f, 0.f, 0.f};

  // pass 1: m 0..3 (irr0 for m0, irr1 for m1..3)
#pragma unroll 2
  for (int ks = 0; ks < 8; ++ks) {
    const int kk = ks << 5;
    s16x8 b00 = *reinterpret_cast<const s16x8*>(wtB + kk);
    s16x8 b01 = *reinterpret_cast<const s16x8*>(wtB + 4096 + kk);
    s16x8 b10 = *reinterpret_cast<const s16x8*>(wtB + 65536 + kk);
    s16x8 b11 = *reinterpret_cast<const s16x8*>(wtB + 65536 + 4096 + kk);
    {
      s16x8 a = *reinterpret_cast<const s16x8*>(xsA + kk);
      accA[0][0] = __builtin_amdgcn_mfma_f32_16x16x32_bf16(a, b00, accA[0][0], 0, 0, 0);
      accA[0][1] = __builtin_amdgcn_mfma_f32_16x16x32_bf16(a, b01, accA[0][1], 0, 0, 0);
    }
#pragma unroll
    for (int m = 1; m < 4; ++m) {
      s16x8 a = *reinterpret_cast<const s16x8*>(xsA + m * XS_MS + kk);
      accA[m][0] = __builtin_amdgcn_mfma_f32_16x16x32_bf16(a, b10, accA[m][0], 0, 0, 0);
      accA[m][1] = __builtin_amdgcn_mfma_f32_16x16x32_bf16(a, b11, accA[m][1], 0, 0, 0);
    }
  }

  f32x4 accB[5][2];  // m = 4..8 (irr2)
#pragma unroll
  for (int m = 0; m < 5; ++m)
#pragma unroll
    for (int ct = 0; ct < 2; ++ct) accB[m][ct] = (f32x4){0.f, 0.f, 0.f, 0.f};

  // pass 2: m 4..8
#pragma unroll 2
  for (int ks = 0; ks < 8; ++ks) {
    const int kk = ks << 5;
    s16x8 b20 = *reinterpret_cast<const s16x8*>(wtB + 2 * 65536 + kk);
    s16x8 b21 = *reinterpret_cast<const s16x8*>(wtB + 2 * 65536 + 4096 + kk);
#pragma unroll
    for (int m = 0; m < 5; ++m) {
      s16x8 a = *reinterpret_cast<const s16x8*>(xsA + (m + 4) * XS_MS + kk);
      accB[m][0] = __builtin_amdgcn_mfma_f32_16x16x32_bf16(a, b20, accB[m][0], 0, 0, 0);
      accB[m][1] = __builtin_amdgcn_mfma_f32_16x16x32_bf16(a, b21, accB[m][1], 0, 0, 0);
    }
  }
  __syncthreads();  // xs fully consumed by ALL waves; stage may alias it

  // ---- per-wave out-stage (9472 B slice of smem), wave-internal sync only ----
  float* stgw = reinterpret_cast<float*>(smem) + w * (POSB * STG_ROW);
  const int posb = (l >> 4) << 2;
  f32x4* o4 = reinterpret_cast<f32x4*>(out) + blk * 9216 + w * 72;

#pragma unroll
  for (int ct = 0; ct < 2; ++ct) {
    // scatter acc -> stgw[pos][cr*9 + m]  (fp32, ~2-way banks: free)
#pragma unroll
    for (int m = 0; m < 9; ++m) {
#pragma unroll
      for (int j = 0; j < 4; ++j) {
        float v = (m < 4) ? accA[m][ct][j] : accB[m - 4][ct][j];
        stgw[(posb + j) * STG_ROW + cr * 9 + m] = v;
      }
    }
    asm volatile("s_waitcnt lgkmcnt(0)" ::: "memory");
    // coalesced float4 NON-TEMPORAL store of this wave's 16c x 9m slice:
    // out is write-once, never re-read -> keep it out of L2/L3 so x stays
    // resident across bench iterations.
#pragma unroll
    for (int q = 0; q < 9; ++q) {
      const int e = l + (q << 6);                 // 0..575 float4s
      const int pos = (int)((unsigned)e / 36u);
      const int rem = e - pos * 36;
      f32x4 v = *reinterpret_cast<const f32x4*>(stgw + pos * STG_ROW + (rem << 2));
      __builtin_nontemporal_store(v, &o4[pos * 576 + ct * 36 + rem]);
    }
    asm volatile("s_waitcnt lgkmcnt(0)" ::: "memory");  // drain reads before next ct writes
  }
}

extern "C" void kernel_launch(void* const* d_in, const int* in_sizes, int n_in,
                              void* d_out, int out_size, void* d_ws, size_t ws_size,
                              hipStream_t stream) {
  const float* x = (const float*)d_in[0];
  const float* w0 = (const float*)d_in[1];
  const float* w1 = (const float*)d_in[2];
  const float* w2 = (const float*)d_in[3];
  unsigned short* wt = (unsigned short*)d_ws;  // 3*256*256 bf16 = 384 KB
  float* out = (float*)d_out;

  prep_w<<<48, 256, 0, stream>>>(w0, w1, w2, wt);

  (void)hipFuncSetAttribute(reinterpret_cast<const void*>(eqlin_main),
                            hipFuncAttributeMaxDynamicSharedMemorySize, SMEM_BYTES);
  eqlin_main<<<2048, 512, SMEM_BYTES, stream>>>(x, wt, out);
}